// Round 13
// baseline (330.061 us; speedup 1.0000x reference)
//
#include <hip/hip_runtime.h>
#include <hip/hip_bf16.h>
#include <math.h>

// B=4, T=2048, C=1024, H=16, Dh=64.

typedef __attribute__((ext_vector_type(8))) short short8;   // 8 bf16 (4 VGPRs)
typedef __attribute__((ext_vector_type(4))) float f32x4;

__device__ __forceinline__ short f2bf(float f) {
    __hip_bfloat16 h = __float2bfloat16(f);
    return *reinterpret_cast<short*>(&h);
}
__device__ __forceinline__ float bf2f(short s) {
    __hip_bfloat16 h = *reinterpret_cast<__hip_bfloat16*>(&s);
    return __bfloat162float(h);
}

#define MFMA16(a, b, c) __builtin_amdgcn_mfma_f32_16x16x32_bf16((a), (b), (c), 0, 0, 0)

// async 16B global->LDS (lds dest: wave-uniform base + lane*16)
__device__ __forceinline__ void gload_lds16(const short* g, short* l) {
    __builtin_amdgcn_global_load_lds(
        (const __attribute__((address_space(1))) void*)g,
        (__attribute__((address_space(3))) void*)l, 16, 0, 0);
}

// ---------------------------------------------------------------------------
// Dtype sniff: fp32 inputs (flag=1) vs bf16 (flag=0).
// ---------------------------------------------------------------------------
__global__ void sniff_kernel(const unsigned int* __restrict__ xb,
                             unsigned int* __restrict__ flag)
{
    __shared__ int cnt;
    if (threadIdx.x == 0) cnt = 0;
    __syncthreads();
    int c = 0;
    for (int i = threadIdx.x; i < 4096; i += 256) {
        unsigned e = (xb[i] >> 7) & 0xFFu;
        if (e >= 96u && e <= 142u) ++c;
    }
    atomicAdd(&cnt, c);
    __syncthreads();
    if (threadIdx.x == 0) *flag = (cnt < 2048) ? 1u : 0u;
}

// ---------------------------------------------------------------------------
// FUSED prep kernel (cvt_x + both weight transposes).
// Blocks 0..4095:      x -> bf16 copy (8 elems/thread).
// Blocks 4096..4863:   w_attn^T (1024x3072 -> [3072][1024] bf16).
// Blocks 4864..5119:   w_proj^T (1024x1024 -> [1024][1024] bf16).
// ---------------------------------------------------------------------------
__global__ __launch_bounds__(256)
void prep_kernel(const void* __restrict__ x, short* __restrict__ Xb,
                 const void* __restrict__ w_attn, short* __restrict__ Wta,
                 const void* __restrict__ w_proj, short* __restrict__ Wtp,
                 const unsigned int* __restrict__ flagp)
{
    const bool f32in = (*flagp != 0u);
    const int bid = blockIdx.x;
    if (bid < 4096) {
        const size_t i = ((size_t)bid * 256 + threadIdx.x) * 8;
        if (f32in) {
            const float* f = (const float*)x + i;
            f32x4 u0 = *(const f32x4*)f;
            f32x4 u1 = *(const f32x4*)(f + 4);
            short8 v;
#pragma unroll
            for (int j = 0; j < 4; ++j) { v[j] = f2bf(u0[j]); v[j + 4] = f2bf(u1[j]); }
            *(short8*)(Xb + i) = v;
        } else {
            *(short8*)(Xb + i) = *(const short8*)((const short*)x + i);
        }
        return;
    }
    // transpose branches
    __shared__ short tile[64][65];
    const void* in; short* out; int R, C, bx, by;
    if (bid < 4864) {
        const int b2 = bid - 4096;               // 768 blocks = 48 x 16
        in = w_attn; out = Wta; R = 1024; C = 3072;
        bx = (b2 % 48) * 64; by = (b2 / 48) * 64;
    } else {
        const int b2 = bid - 4864;               // 256 blocks = 16 x 16
        in = w_proj; out = Wtp; R = 1024; C = 1024;
        bx = (b2 % 16) * 64; by = (b2 / 16) * 64;
    }
    const int tx = threadIdx.x & 63;
    const int ty = threadIdx.x >> 6;
#pragma unroll
    for (int i = 0; i < 64; i += 4) {
        size_t idx = (size_t)(by + ty + i) * C + bx + tx;
        tile[ty + i][tx] = f32in ? f2bf(((const float*)in)[idx])
                                 : ((const short*)in)[idx];
    }
    __syncthreads();
#pragma unroll
    for (int i = 0; i < 64; i += 4)
        out[(size_t)(bx + ty + i) * R + by + tx] = tile[tx][ty + i];
}

// ---------------------------------------------------------------------------
// GEMM: C = A[M][K] (bf16) @ B (Bt[N][K] bf16) + bias.
// R13: 256x128 TILE, 512 threads / 8 waves (wave grid 4Mx2N, 64x64 out/wave
// — fragment shapes identical to the proven 128² kernel).  Sync ledger is
// VERBATIM R7/R12 (3-buffer counted-vmcnt, one raw s_barrier per K-step):
//   prologue stages tiles 0,1 (6 loads/thread out); per step
//   s_waitcnt vmcnt(3) (own oldest stage done; cross-wave via barrier),
//   stage(k+2), compute.  Race-free by induction from R7.
// Why bigger tile: panel re-read traffic 770 -> 576 MB (B-panels read by 32
// not 64 blocks); LDS 72 KB -> 2 blocks/CU = 4 waves/SIMD (was 3); barrier
// amortization per output 2x.
// R12 bank swizzle carried verbatim (same row stride 32 shorts): source slot
// pre-XOR + read slot XOR ((ar>>1)&3) -> conflicts stay 0.
// EPI=1 (QKV): scatter Q,K [BH][T][64], V transposed [BH][64][T].
//   Q outputs PRE-SCALED by 0.125*log2(e) so attn uses exp2 directly.
// EPI=0 (proj): row-major out, dtype per flag.
// ---------------------------------------------------------------------------
template <int EPI>
__global__ __launch_bounds__(512)
void gemm_kernel(const short* __restrict__ A,
                 const short* __restrict__ Bt,
                 const void* __restrict__ bias,
                 void* __restrict__ O0,
                 short* __restrict__ O1,
                 short* __restrict__ O2,
                 int M, int N, int K,
                 const unsigned int* __restrict__ flagp)
{
    const bool f32io = (*flagp != 0u);
    __shared__ __align__(16) short ldsA[3 * 256 * 32];  // 3-buf [m][k] stride 32
    __shared__ __align__(16) short ldsB[3 * 128 * 32];  // 3-buf [n][k]

    const int tid = threadIdx.x;
    const int lane = tid & 63;
    const int wid = tid >> 6;            // 0..7
    const int wm = (wid >> 1) * 64;      // 0,64,128,192  (M-band)
    const int wn = (wid & 1) * 64;       // 0,64          (N-band)
    const int tile_m = blockIdx.y * 256;
    const int tile_n = blockIdx.x * 128;

    f32x4 acc[4][4];
#pragma unroll
    for (int i = 0; i < 4; ++i)
#pragma unroll
        for (int j = 0; j < 4; ++j) acc[i][j] = (f32x4){0.f, 0.f, 0.f, 0.f};

    const int ar = lane & 15;
    const int aq = (lane >> 4) * 8;                  // 16B slot offset, shorts
    const int arx = ((ar >> 1) & 3) << 3;            // read-side XOR, shorts
    const int lrow = lane >> 2;                      // 0..15 staging row
    // pre-swizzled source slot: (lane&3) ^ ((lrow>>1)&3)
    const int scol = (((lane & 3) ^ ((lane >> 3) & 3)) << 3);

    // stage K-chunk k0 into buffer bsel: A 2 calls + B 1 call per thread
    auto stage = [&](int k0, int bsel) {
#pragma unroll
        for (int p = 0; p < 2; ++p) {
            int c = wid * 2 + p;                     // 0..15 -> A rows c*16+lrow
            int row = c * 16 + lrow;
            gload_lds16(A + (size_t)(tile_m + row) * K + k0 + scol,
                        ldsA + bsel * 8192 + c * 512);
        }
        {
            int row = wid * 16 + lrow;               // 0..127 B rows
            gload_lds16(Bt + (size_t)(tile_n + row) * K + k0 + scol,
                        ldsB + bsel * 4096 + wid * 512);
        }
    };

    stage(0, 0);                          // 3 in flight
    stage(32, 1);                         // 6 in flight
    int cur = 0;

    for (int k0 = 0; k0 < K; k0 += 32) {
        // wait for own OLDEST stage only (3 loads); cross-wave via barrier.
        if (k0 + 32 < K) {
            asm volatile("s_waitcnt vmcnt(3)\n\ts_barrier" ::: "memory");
        } else {
            asm volatile("s_waitcnt vmcnt(0)\n\ts_barrier" ::: "memory");
        }

        int nb = cur + 2; if (nb >= 3) nb -= 3;
        if (k0 + 64 < K) stage(k0 + 64, nb);

        const short* Ab = ldsA + cur * 8192;
        const short* Bb = ldsB + cur * 4096;
        short8 af[4], bfr[4];
#pragma unroll
        for (int i = 0; i < 4; ++i)
            af[i] = *(const short8*)(Ab + (wm + i * 16 + ar) * 32 + (aq ^ arx));
#pragma unroll
        for (int j = 0; j < 4; ++j)
            bfr[j] = *(const short8*)(Bb + (wn + j * 16 + ar) * 32 + (aq ^ arx));
#pragma unroll
        for (int i = 0; i < 4; ++i)
#pragma unroll
            for (int j = 0; j < 4; ++j)
                acc[i][j] = MFMA16(af[i], bfr[j], acc[i][j]);

        ++cur; if (cur == 3) cur = 0;
    }

    const int colq = lane & 15;
    const int rowq = (lane >> 4) * 4;
#pragma unroll
    for (int j = 0; j < 4; ++j) {
        int gn = tile_n + wn + j * 16 + colq;
        float bv = f32io ? ((const float*)bias)[gn] : bf2f(((const short*)bias)[gn]);
#pragma unroll
        for (int i = 0; i < 4; ++i) {
#pragma unroll
            for (int r = 0; r < 4; ++r) {
                int gm = tile_m + wm + i * 16 + rowq + r;
                float val = acc[i][j][r] + bv;
                if (EPI == 0) {
                    if (f32io) ((float*)O0)[(size_t)gm * N + gn] = val;
                    else       ((short*)O0)[(size_t)gm * N + gn] = f2bf(val);
                } else {
                    int which = gn >> 10;
                    int c = gn & 1023;
                    int h = c >> 6;
                    int d = c & 63;
                    int b = gm >> 11;
                    int t = gm & 2047;
                    size_t bh = (size_t)(b * 16 + h);
                    // Q pre-scaled: scale * log2(e) = 0.125 * 1.44269504...
                    short o = f2bf(which == 0 ? val * 0.18033688011112042f : val);
                    if (which == 0)      ((short*)O0)[(bh * 2048 + t) * 64 + d] = o;
                    else if (which == 1) O1[(bh * 2048 + t) * 64 + d] = o;
                    else                 O2[(bh * 64 + d) * 2048 + t] = o;  // V^T
                }
            }
        }
    }
}

// ---------------------------------------------------------------------------
// Flash attention, causal, fixed-base softmax (exact: |scores| << 88).
// Q,K: [BH][2048][64], Vt: [BH][64][2048] bf16.  Y: [B][T][C] bf16.
// R6 champion structure (96.7 µs, FETCH 40 MB, VGPR 64) — FROZEN.
//  - LDS exactly 40960 B (K/V dbuf 32768 + XOR-swizzled pbuf 8192);
//    grid 1024 = 4 blocks/CU, launch_bounds(256,4) -> VGPR 64 (no spill;
//    R8/R9 lesson: min-waves bound below live set = scratch spill).
//  - Paired tiles (t, 31-t): 33 uniform steps/block; XCD chunking.
//  - 1-barrier dbuf pipeline; mask-split exp path; s_setprio on MFMA.
// ---------------------------------------------------------------------------
__global__ __launch_bounds__(256, 4)
void attn_kernel(const short* __restrict__ Q,
                 const short* __restrict__ Kp_,
                 const short* __restrict__ Vt,
                 short* __restrict__ Y)
{
    __shared__ __align__(16) short ldsK[2 * 64 * 64];  // dbuf [key][d], swizzled
    __shared__ __align__(16) short ldsV[2 * 64 * 64];  // dbuf [d][key], swizzled
    __shared__ __align__(16) short pbuf[4][16 * 64];   // per-wave P, XOR-swizzled

    const int tid = threadIdx.x;
    const int lane = tid & 63;
    const int wv = tid >> 6;                  // 0..3
    const int m16 = lane & 15;
    const int quad = lane >> 4;

    // XCD decode: 1024 blocks; xcd = fid&7; 8 bh per XCD; 16 pairs per bh.
    const int fid = blockIdx.x;
    const int xcd = fid & 7;
    const int slot = fid >> 3;                // 0..127
    const int bh = (xcd << 3) | (slot >> 4);  // 0..63
    const int g = slot & 15;                  // pair id 0..15

    const int b = bh >> 4, h = bh & 15;

    const short* Qp = Q   + (size_t)bh * 2048 * 64;
    const short* Kp = Kp_ + (size_t)bh * 2048 * 64;
    const short* Vp = Vt  + (size_t)bh * 64 * 2048;
    short* pw = pbuf[wv];

    const int srow = lane >> 3;                           // 0..7 within call
    const int sw = (((lane & 7) ^ (srow & 7)) << 3);      // swizzled col, shorts
    const int swr = ((m16 & 7) << 3);                     // K/V read-side XOR
    const int pswr = swr;                                  // pbuf read XOR (q=m16)

    // stage K/V tile at key-offset kb into buffer bsel (4 gload_lds16/thread)
    auto stage = [&](int kb, int bsel) {
#pragma unroll
        for (int p = 0; p < 2; ++p) {
            const int c8 = wv * 2 + p;
            const int row = c8 * 8 + srow;
            gload_lds16(Kp + (size_t)(kb + row) * 64 + sw,
                        ldsK + bsel * 4096 + c8 * 512);
            gload_lds16(Vp + (size_t)row * 2048 + kb + sw,
                        ldsV + bsel * 4096 + c8 * 512);
        }
    };

#pragma unroll
    for (int pass = 0; pass < 2; ++pass) {
        const int t = pass ? (31 - g) : g;        // 64-row tile index 0..31
        const int qbase = t * 64 + wv * 16;       // this wave's 16 q-rows

        stage(0, 0);                              // prologue for this pass

        short8 aq0 = *(const short8*)(Qp + (size_t)(qbase + m16) * 64 + quad * 8);
        short8 aq1 = *(const short8*)(Qp + (size_t)(qbase + m16) * 64 + 32 + quad * 8);

        __syncthreads();                          // implicit vmcnt(0): buf0 ready
        int cur = 0;

        f32x4 o[4];
#pragma unroll
        for (int dt = 0; dt < 4; ++dt) o[dt] = (f32x4){0.f, 0.f, 0.f, 0.f};
        float lrow[4] = {0.f, 0.f, 0.f, 0.f};

        for (int kt = 0; kt <= t; ++kt) {
            const int kb = kt << 6;
            if (kt < t) stage(kb + 64, cur ^ 1);  // issue-early (overlaps)

            const short* kbase = ldsK + cur * 4096;
            const short* vbase = ldsV + cur * 4096;

            // ---- QK^T: 4 key-blocks x 2 k-chunks ----
            f32x4 s[4];
            __builtin_amdgcn_s_setprio(1);
#pragma unroll
            for (int c = 0; c < 4; ++c) {
                const short* kr = kbase + (c * 16 + m16) * 64;
                short8 kf0 = *(const short8*)(kr + ((quad * 8) ^ swr));
                short8 kf1 = *(const short8*)(kr + ((quad * 8 + 32) ^ swr));
                f32x4 z = (f32x4){0.f, 0.f, 0.f, 0.f};
                z = MFMA16(aq0, kf0, z);
                z = MFMA16(aq1, kf1, z);
                s[c] = z;
            }
            __builtin_amdgcn_s_setprio(0);

            // ---- exp + P store (fixed-base; Q pre-scaled).  Mask-split:
            // kt < t  -> causal mask provably dead (kb+63 < qbase).
            // kt == t -> masked path (runs once per pass). ----
            if (kt < t) {
#pragma unroll
                for (int c = 0; c < 4; ++c) {
#pragma unroll
                    for (int r = 0; r < 4; ++r) {
                        const int qrow = quad * 4 + r;
                        float p = exp2f(s[c][r]);
                        lrow[r] += p;
                        pw[qrow * 64 + ((c * 16 + m16) ^ ((qrow & 7) << 3))] = f2bf(p);
                    }
                }
            } else {
#pragma unroll
                for (int c = 0; c < 4; ++c) {
                    const int key = kb + c * 16 + m16;
                    const bool needmask = (kb + c * 16 + 15 > qbase);
#pragma unroll
                    for (int r = 0; r < 4; ++r) {
                        const int qrow = quad * 4 + r;
                        float p = exp2f(s[c][r]);
                        if (needmask && key > qbase + qrow) p = 0.f;
                        lrow[r] += p;
                        pw[qrow * 64 + ((c * 16 + m16) ^ ((qrow & 7) << 3))] = f2bf(p);
                    }
                }
            }

            // P (C-layout) -> A-operand via per-wave LDS round-trip
            asm volatile("" ::: "memory");
            short8 ap0 = *(const short8*)(pw + m16 * 64 + ((quad * 8) ^ pswr));
            short8 ap1 = *(const short8*)(pw + m16 * 64 + ((quad * 8 + 32) ^ pswr));
            asm volatile("" ::: "memory");

            // ---- PV: 4 d-blocks x 2 k-chunks ----
            __builtin_amdgcn_s_setprio(1);
#pragma unroll
            for (int dt = 0; dt < 4; ++dt) {
                const short* vr = vbase + (dt * 16 + m16) * 64;
                short8 vf0 = *(const short8*)(vr + ((quad * 8) ^ swr));
                short8 vf1 = *(const short8*)(vr + ((quad * 8 + 32) ^ swr));
                o[dt] = MFMA16(ap0, vf0, o[dt]);
                o[dt] = MFMA16(ap1, vf1, o[dt]);
            }
            __builtin_amdgcn_s_setprio(0);

            __syncthreads();              // one barrier/step: drains next-stage
            cur ^= 1;
        }

        // row-sum reduce over the 16 key-lanes (xor within m16 group)
        float linv[4];
#pragma unroll
        for (int r = 0; r < 4; ++r) {
            float sm = lrow[r];
#pragma unroll
            for (int off = 1; off < 16; off <<= 1)
                sm += __shfl_xor(sm, off);
            linv[r] = 1.0f / sm;
        }
#pragma unroll
        for (int dt = 0; dt < 4; ++dt) {
#pragma unroll
            for (int r = 0; r < 4; ++r) {
                int row = qbase + quad * 4 + r;
                int col = h * 64 + dt * 16 + m16;
                Y[((size_t)(b * 2048 + row)) * 1024 + col] = f2bf(o[dt][r] * linv[r]);
            }
        }
        // pass boundary safe: trailing __syncthreads of the kt-loop ran after
        // all LDS reads of the final tile.
    }
}

// ---------------------------------------------------------------------------
extern "C" void kernel_launch(void* const* d_in, const int* in_sizes, int n_in,
                              void* d_out, int out_size, void* d_ws, size_t ws_size,
                              hipStream_t stream)
{
    const void* x      = d_in[0];
    const void* w_attn = d_in[1];
    const void* b_attn = d_in[2];
    const void* w_proj = d_in[3];
    const void* b_proj = d_in[4];

    char* ws = (char*)d_ws;
    unsigned int* flag = (unsigned int*)(ws + 0);
    short* Wta = (short*)(ws + 256);
    short* Wtp = (short*)(ws + 6291712);
    short* Qb  = (short*)(ws + 8388864);
    short* Kb  = (short*)(ws + 25166080);
    short* Vtb = (short*)(ws + 41943296);
    short* Yb  = (short*)(ws + 58720512);
    // Xb (bf16 x) REUSES the Yb slot: Xb's lifetime (prep -> QKV gemm)
    // ends before Yb's begins (attn -> proj gemm); same stream, sequential.
    short* Xb  = (short*)(ws + 58720512);

    sniff_kernel<<<1, 256, 0, stream>>>((const unsigned int*)x, flag);
    prep_kernel<<<dim3(5120), 256, 0, stream>>>(x, Xb, w_attn, Wta, w_proj, Wtp, flag);
    gemm_kernel<1><<<dim3(24, 32), 512, 0, stream>>>(Xb, Wta, b_attn, Qb, Kb, Vtb,
                                                     8192, 3072, 1024, flag);
    attn_kernel<<<dim3(1024), 256, 0, stream>>>(Qb, Kb, Vtb, Yb);
    gemm_kernel<0><<<dim3(8, 32), 512, 0, stream>>>(Yb, Wtp, b_proj, d_out, nullptr, nullptr,
                                                    8192, 1024, 1024, flag);
}

// Round 14
// 318.897 us; speedup vs baseline: 1.0350x; 1.0350x over previous
//
#include <hip/hip_runtime.h>
#include <hip/hip_bf16.h>
#include <math.h>

// B=4, T=2048, C=1024, H=16, Dh=64.

typedef __attribute__((ext_vector_type(8))) short short8;   // 8 bf16 (4 VGPRs)
typedef __attribute__((ext_vector_type(4))) float f32x4;

__device__ __forceinline__ short f2bf(float f) {
    __hip_bfloat16 h = __float2bfloat16(f);
    return *reinterpret_cast<short*>(&h);
}
__device__ __forceinline__ float bf2f(short s) {
    __hip_bfloat16 h = *reinterpret_cast<__hip_bfloat16*>(&s);
    return __bfloat162float(h);
}

#define MFMA16(a, b, c) __builtin_amdgcn_mfma_f32_16x16x32_bf16((a), (b), (c), 0, 0, 0)

// async 16B global->LDS (lds dest: wave-uniform base + lane*16)
__device__ __forceinline__ void gload_lds16(const short* g, short* l) {
    __builtin_amdgcn_global_load_lds(
        (const __attribute__((address_space(1))) void*)g,
        (__attribute__((address_space(3))) void*)l, 16, 0, 0);
}

// ---------------------------------------------------------------------------
// R14: FUSED prep kernel with SELF-SNIFF (was sniff + prep = 2 dispatches).
// Each block determines the input dtype locally from x's first 4096 words
// (16 KB, L2-hot after the first block); block 0 publishes the flag for the
// downstream GEMM/attn kernels (stream order guarantees visibility).
// Blocks 0..4095:      x -> bf16 copy (8 elems/thread).
// Blocks 4096..4863:   w_attn^T (1024x3072 -> [3072][1024] bf16).
// Blocks 4864..5119:   w_proj^T (1024x1024 -> [1024][1024] bf16).
// ---------------------------------------------------------------------------
__global__ __launch_bounds__(256)
void prep_kernel(const void* __restrict__ x, short* __restrict__ Xb,
                 const void* __restrict__ w_attn, short* __restrict__ Wta,
                 const void* __restrict__ w_proj, short* __restrict__ Wtp,
                 unsigned int* __restrict__ flagp)
{
    // ---- local sniff (replicates the old sniff_kernel exactly) ----
    __shared__ int cnt;
    if (threadIdx.x == 0) cnt = 0;
    __syncthreads();
    {
        const unsigned int* xb = (const unsigned int*)x;
        int c = 0;
        for (int i = threadIdx.x; i < 4096; i += 256) {
            unsigned e = (xb[i] >> 7) & 0xFFu;
            if (e >= 96u && e <= 142u) ++c;
        }
        atomicAdd(&cnt, c);
    }
    __syncthreads();
    const bool f32in = (cnt < 2048);
    const int bid = blockIdx.x;
    if (bid == 0 && threadIdx.x == 0) *flagp = f32in ? 1u : 0u;

    if (bid < 4096) {
        const size_t i = ((size_t)bid * 256 + threadIdx.x) * 8;
        if (f32in) {
            const float* f = (const float*)x + i;
            f32x4 u0 = *(const f32x4*)f;
            f32x4 u1 = *(const f32x4*)(f + 4);
            short8 v;
#pragma unroll
            for (int j = 0; j < 4; ++j) { v[j] = f2bf(u0[j]); v[j + 4] = f2bf(u1[j]); }
            *(short8*)(Xb + i) = v;
        } else {
            *(short8*)(Xb + i) = *(const short8*)((const short*)x + i);
        }
        return;
    }
    // transpose branches
    __shared__ short tile[64][65];
    const void* in; short* out; int R, C, bx, by;
    if (bid < 4864) {
        const int b2 = bid - 4096;               // 768 blocks = 48 x 16
        in = w_attn; out = Wta; R = 1024; C = 3072;
        bx = (b2 % 48) * 64; by = (b2 / 48) * 64;
    } else {
        const int b2 = bid - 4864;               // 256 blocks = 16 x 16
        in = w_proj; out = Wtp; R = 1024; C = 1024;
        bx = (b2 % 16) * 64; by = (b2 / 16) * 64;
    }
    const int tx = threadIdx.x & 63;
    const int ty = threadIdx.x >> 6;
#pragma unroll
    for (int i = 0; i < 64; i += 4) {
        size_t idx = (size_t)(by + ty + i) * C + bx + tx;
        tile[ty + i][tx] = f32in ? f2bf(((const float*)in)[idx])
                                 : ((const short*)in)[idx];
    }
    __syncthreads();
#pragma unroll
    for (int i = 0; i < 64; i += 4)
        out[(size_t)(bx + ty + i) * R + by + tx] = tile[tx][ty + i];
}

// ---------------------------------------------------------------------------
// GEMM: C = A[M][K] (bf16) @ B (Bt[N][K] bf16) + bias.  128x128 tile, BK=32.
// R14 = VERBATIM R12 (measured family floor: 97 µs QKV / 33 µs proj;
// conflicts 0, FETCH 71.75 MB).  Four structure variants bracketed the
// family (R4 103 / R6 97 / R7 96 / R13 106): per-step fabric is binding,
// not staging, not conflicts, not tile size.
//  - 3-buffer counted-vmcnt pipeline (one raw s_barrier per K-step).
//  - T2 bank swizzle (source slot pre-XOR + read slot XOR ((ar>>1)&3)):
//    SQ_LDS_BANK_CONFLICT 6.29M -> 0 (timing-null at 2-phase, kept free).
// EPI=1 (QKV): scatter Q,K [BH][T][64], V transposed [BH][64][T].
//   Q outputs PRE-SCALED by 0.125*log2(e) so attn uses exp2 directly.
// EPI=0 (proj): row-major out, dtype per flag.
// ---------------------------------------------------------------------------
template <int EPI>
__global__ __launch_bounds__(256)
void gemm_kernel(const short* __restrict__ A,
                 const short* __restrict__ Bt,
                 const void* __restrict__ bias,
                 void* __restrict__ O0,
                 short* __restrict__ O1,
                 short* __restrict__ O2,
                 int M, int N, int K,
                 const unsigned int* __restrict__ flagp)
{
    const bool f32io = (*flagp != 0u);
    __shared__ __align__(16) short ldsA[3 * 128 * 32];  // 3-buf [m][k] stride 32
    __shared__ __align__(16) short ldsB[3 * 128 * 32];

    const int tid = threadIdx.x;
    const int lane = tid & 63;
    const int wv = tid >> 6;
    const int wm = (wv & 1) * 64;
    const int wn = (wv >> 1) * 64;
    const int tile_m = blockIdx.y * 128;
    const int tile_n = blockIdx.x * 128;

    f32x4 acc[4][4];
#pragma unroll
    for (int i = 0; i < 4; ++i)
#pragma unroll
        for (int j = 0; j < 4; ++j) acc[i][j] = (f32x4){0.f, 0.f, 0.f, 0.f};

    const int ar = lane & 15;
    const int aq = (lane >> 4) * 8;                  // 16B slot offset, shorts
    const int arx = ((ar >> 1) & 3) << 3;            // read-side XOR, shorts
    const int lrow = lane >> 2;                      // 0..15 staging row
    // pre-swizzled source slot: (lane&3) ^ ((lrow>>1)&3)
    const int scol = (((lane & 3) ^ ((lane >> 3) & 3)) << 3);

    // stage K-chunk k0 into buffer bsel (4 gload_lds16/thread)
    auto stage = [&](int k0, int bsel) {
#pragma unroll
        for (int p = 0; p < 2; ++p) {
            int c = wv * 2 + p;
            int row = c * 16 + lrow;
            gload_lds16(A + (size_t)(tile_m + row) * K + k0 + scol,
                        ldsA + bsel * 4096 + c * 512);
            gload_lds16(Bt + (size_t)(tile_n + row) * K + k0 + scol,
                        ldsB + bsel * 4096 + c * 512);
        }
    };

    stage(0, 0);                          //  4 in flight
    stage(32, 1);                         //  8 in flight
    int cur = 0;

    for (int k0 = 0; k0 < K; k0 += 32) {
        // wait for the OLDEST stage (tile k0) only; keep the next in flight.
        if (k0 + 32 < K) {
            asm volatile("s_waitcnt vmcnt(4)\n\ts_barrier" ::: "memory");
        } else {
            asm volatile("s_waitcnt vmcnt(0)\n\ts_barrier" ::: "memory");
        }

        int nb = cur + 2; if (nb >= 3) nb -= 3;
        if (k0 + 64 < K) stage(k0 + 64, nb);

        const short* Ab = ldsA + cur * 4096;
        const short* Bb = ldsB + cur * 4096;
        short8 af[4], bfr[4];
#pragma unroll
        for (int i = 0; i < 4; ++i)
            af[i] = *(const short8*)(Ab + (wm + i * 16 + ar) * 32 + (aq ^ arx));
#pragma unroll
        for (int j = 0; j < 4; ++j)
            bfr[j] = *(const short8*)(Bb + (wn + j * 16 + ar) * 32 + (aq ^ arx));
#pragma unroll
        for (int i = 0; i < 4; ++i)
#pragma unroll
            for (int j = 0; j < 4; ++j)
                acc[i][j] = MFMA16(af[i], bfr[j], acc[i][j]);

        ++cur; if (cur == 3) cur = 0;
    }

    const int colq = lane & 15;
    const int rowq = (lane >> 4) * 4;
#pragma unroll
    for (int j = 0; j < 4; ++j) {
        int gn = tile_n + wn + j * 16 + colq;
        float bv = f32io ? ((const float*)bias)[gn] : bf2f(((const short*)bias)[gn]);
#pragma unroll
        for (int i = 0; i < 4; ++i) {
#pragma unroll
            for (int r = 0; r < 4; ++r) {
                int gm = tile_m + wm + i * 16 + rowq + r;
                float val = acc[i][j][r] + bv;
                if (EPI == 0) {
                    if (f32io) ((float*)O0)[(size_t)gm * N + gn] = val;
                    else       ((short*)O0)[(size_t)gm * N + gn] = f2bf(val);
                } else {
                    int which = gn >> 10;
                    int c = gn & 1023;
                    int h = c >> 6;
                    int d = c & 63;
                    int b = gm >> 11;
                    int t = gm & 2047;
                    size_t bh = (size_t)(b * 16 + h);
                    // Q pre-scaled: scale * log2(e) = 0.125 * 1.44269504...
                    short o = f2bf(which == 0 ? val * 0.18033688011112042f : val);
                    if (which == 0)      ((short*)O0)[(bh * 2048 + t) * 64 + d] = o;
                    else if (which == 1) O1[(bh * 2048 + t) * 64 + d] = o;
                    else                 O2[(bh * 64 + d) * 2048 + t] = o;  // V^T
                }
            }
        }
    }
}

// ---------------------------------------------------------------------------
// Flash attention, causal, fixed-base softmax (exact: |scores| << 88).
// Q,K: [BH][2048][64], Vt: [BH][64][2048] bf16.  Y: [B][T][C] bf16.
// R6 champion structure (96.7 µs, FETCH 40 MB, VGPR 64) — FROZEN.
//  - LDS exactly 40960 B (K/V dbuf 32768 + XOR-swizzled pbuf 8192);
//    grid 1024 = 4 blocks/CU, launch_bounds(256,4) -> VGPR 64 (no spill;
//    R8/R9 lesson: min-waves bound below live set = scratch spill).
//  - Paired tiles (t, 31-t): 33 uniform steps/block; XCD chunking.
//  - 1-barrier dbuf pipeline; mask-split exp path; s_setprio on MFMA.
// ---------------------------------------------------------------------------
__global__ __launch_bounds__(256, 4)
void attn_kernel(const short* __restrict__ Q,
                 const short* __restrict__ Kp_,
                 const short* __restrict__ Vt,
                 short* __restrict__ Y)
{
    __shared__ __align__(16) short ldsK[2 * 64 * 64];  // dbuf [key][d], swizzled
    __shared__ __align__(16) short ldsV[2 * 64 * 64];  // dbuf [d][key], swizzled
    __shared__ __align__(16) short pbuf[4][16 * 64];   // per-wave P, XOR-swizzled

    const int tid = threadIdx.x;
    const int lane = tid & 63;
    const int wv = tid >> 6;                  // 0..3
    const int m16 = lane & 15;
    const int quad = lane >> 4;

    // XCD decode: 1024 blocks; xcd = fid&7; 8 bh per XCD; 16 pairs per bh.
    const int fid = blockIdx.x;
    const int xcd = fid & 7;
    const int slot = fid >> 3;                // 0..127
    const int bh = (xcd << 3) | (slot >> 4);  // 0..63
    const int g = slot & 15;                  // pair id 0..15

    const int b = bh >> 4, h = bh & 15;

    const short* Qp = Q   + (size_t)bh * 2048 * 64;
    const short* Kp = Kp_ + (size_t)bh * 2048 * 64;
    const short* Vp = Vt  + (size_t)bh * 64 * 2048;
    short* pw = pbuf[wv];

    const int srow = lane >> 3;                           // 0..7 within call
    const int sw = (((lane & 7) ^ (srow & 7)) << 3);      // swizzled col, shorts
    const int swr = ((m16 & 7) << 3);                     // K/V read-side XOR
    const int pswr = swr;                                  // pbuf read XOR (q=m16)

    // stage K/V tile at key-offset kb into buffer bsel (4 gload_lds16/thread)
    auto stage = [&](int kb, int bsel) {
#pragma unroll
        for (int p = 0; p < 2; ++p) {
            const int c8 = wv * 2 + p;
            const int row = c8 * 8 + srow;
            gload_lds16(Kp + (size_t)(kb + row) * 64 + sw,
                        ldsK + bsel * 4096 + c8 * 512);
            gload_lds16(Vp + (size_t)row * 2048 + kb + sw,
                        ldsV + bsel * 4096 + c8 * 512);
        }
    };

#pragma unroll
    for (int pass = 0; pass < 2; ++pass) {
        const int t = pass ? (31 - g) : g;        // 64-row tile index 0..31
        const int qbase = t * 64 + wv * 16;       // this wave's 16 q-rows

        stage(0, 0);                              // prologue for this pass

        short8 aq0 = *(const short8*)(Qp + (size_t)(qbase + m16) * 64 + quad * 8);
        short8 aq1 = *(const short8*)(Qp + (size_t)(qbase + m16) * 64 + 32 + quad * 8);

        __syncthreads();                          // implicit vmcnt(0): buf0 ready
        int cur = 0;

        f32x4 o[4];
#pragma unroll
        for (int dt = 0; dt < 4; ++dt) o[dt] = (f32x4){0.f, 0.f, 0.f, 0.f};
        float lrow[4] = {0.f, 0.f, 0.f, 0.f};

        for (int kt = 0; kt <= t; ++kt) {
            const int kb = kt << 6;
            if (kt < t) stage(kb + 64, cur ^ 1);  // issue-early (overlaps)

            const short* kbase = ldsK + cur * 4096;
            const short* vbase = ldsV + cur * 4096;

            // ---- QK^T: 4 key-blocks x 2 k-chunks ----
            f32x4 s[4];
            __builtin_amdgcn_s_setprio(1);
#pragma unroll
            for (int c = 0; c < 4; ++c) {
                const short* kr = kbase + (c * 16 + m16) * 64;
                short8 kf0 = *(const short8*)(kr + ((quad * 8) ^ swr));
                short8 kf1 = *(const short8*)(kr + ((quad * 8 + 32) ^ swr));
                f32x4 z = (f32x4){0.f, 0.f, 0.f, 0.f};
                z = MFMA16(aq0, kf0, z);
                z = MFMA16(aq1, kf1, z);
                s[c] = z;
            }
            __builtin_amdgcn_s_setprio(0);

            // ---- exp + P store (fixed-base; Q pre-scaled).  Mask-split:
            // kt < t  -> causal mask provably dead (kb+63 < qbase).
            // kt == t -> masked path (runs once per pass). ----
            if (kt < t) {
#pragma unroll
                for (int c = 0; c < 4; ++c) {
#pragma unroll
                    for (int r = 0; r < 4; ++r) {
                        const int qrow = quad * 4 + r;
                        float p = exp2f(s[c][r]);
                        lrow[r] += p;
                        pw[qrow * 64 + ((c * 16 + m16) ^ ((qrow & 7) << 3))] = f2bf(p);
                    }
                }
            } else {
#pragma unroll
                for (int c = 0; c < 4; ++c) {
                    const int key = kb + c * 16 + m16;
                    const bool needmask = (kb + c * 16 + 15 > qbase);
#pragma unroll
                    for (int r = 0; r < 4; ++r) {
                        const int qrow = quad * 4 + r;
                        float p = exp2f(s[c][r]);
                        if (needmask && key > qbase + qrow) p = 0.f;
                        lrow[r] += p;
                        pw[qrow * 64 + ((c * 16 + m16) ^ ((qrow & 7) << 3))] = f2bf(p);
                    }
                }
            }

            // P (C-layout) -> A-operand via per-wave LDS round-trip
            asm volatile("" ::: "memory");
            short8 ap0 = *(const short8*)(pw + m16 * 64 + ((quad * 8) ^ pswr));
            short8 ap1 = *(const short8*)(pw + m16 * 64 + ((quad * 8 + 32) ^ pswr));
            asm volatile("" ::: "memory");

            // ---- PV: 4 d-blocks x 2 k-chunks ----
            __builtin_amdgcn_s_setprio(1);
#pragma unroll
            for (int dt = 0; dt < 4; ++dt) {
                const short* vr = vbase + (dt * 16 + m16) * 64;
                short8 vf0 = *(const short8*)(vr + ((quad * 8) ^ swr));
                short8 vf1 = *(const short8*)(vr + ((quad * 8 + 32) ^ swr));
                o[dt] = MFMA16(ap0, vf0, o[dt]);
                o[dt] = MFMA16(ap1, vf1, o[dt]);
            }
            __builtin_amdgcn_s_setprio(0);

            __syncthreads();              // one barrier/step: drains next-stage
            cur ^= 1;
        }

        // row-sum reduce over the 16 key-lanes (xor within m16 group)
        float linv[4];
#pragma unroll
        for (int r = 0; r < 4; ++r) {
            float sm = lrow[r];
#pragma unroll
            for (int off = 1; off < 16; off <<= 1)
                sm += __shfl_xor(sm, off);
            linv[r] = 1.0f / sm;
        }
#pragma unroll
        for (int dt = 0; dt < 4; ++dt) {
#pragma unroll
            for (int r = 0; r < 4; ++r) {
                int row = qbase + quad * 4 + r;
                int col = h * 64 + dt * 16 + m16;
                Y[((size_t)(b * 2048 + row)) * 1024 + col] = f2bf(o[dt][r] * linv[r]);
            }
        }
        // pass boundary safe: trailing __syncthreads of the kt-loop ran after
        // all LDS reads of the final tile.
    }
}

// ---------------------------------------------------------------------------
extern "C" void kernel_launch(void* const* d_in, const int* in_sizes, int n_in,
                              void* d_out, int out_size, void* d_ws, size_t ws_size,
                              hipStream_t stream)
{
    const void* x      = d_in[0];
    const void* w_attn = d_in[1];
    const void* b_attn = d_in[2];
    const void* w_proj = d_in[3];
    const void* b_proj = d_in[4];

    char* ws = (char*)d_ws;
    unsigned int* flag = (unsigned int*)(ws + 0);
    short* Wta = (short*)(ws + 256);
    short* Wtp = (short*)(ws + 6291712);
    short* Qb  = (short*)(ws + 8388864);
    short* Kb  = (short*)(ws + 25166080);
    short* Vtb = (short*)(ws + 41943296);
    short* Yb  = (short*)(ws + 58720512);
    // Xb (bf16 x) REUSES the Yb slot: Xb's lifetime (prep -> QKV gemm)
    // ends before Yb's begins (attn -> proj gemm); same stream, sequential.
    short* Xb  = (short*)(ws + 58720512);

    prep_kernel<<<dim3(5120), 256, 0, stream>>>(x, Xb, w_attn, Wta, w_proj, Wtp, flag);
    gemm_kernel<1><<<dim3(24, 64), 256, 0, stream>>>(Xb, Wta, b_attn, Qb, Kb, Vtb,
                                                     8192, 3072, 1024, flag);
    attn_kernel<<<dim3(1024), 256, 0, stream>>>(Qb, Kb, Vtb, Yb);
    gemm_kernel<0><<<dim3(8, 64), 256, 0, stream>>>(Yb, Wtp, b_proj, d_out, nullptr, nullptr,
                                                    8192, 1024, 1024, flag);
}

// Round 15
// 308.869 us; speedup vs baseline: 1.0686x; 1.0325x over previous
//
#include <hip/hip_runtime.h>
#include <hip/hip_bf16.h>
#include <math.h>

// B=4, T=2048, C=1024, H=16, Dh=64.

typedef __attribute__((ext_vector_type(8))) short short8;   // 8 bf16 (4 VGPRs)
typedef __attribute__((ext_vector_type(4))) float f32x4;

__device__ __forceinline__ short f2bf(float f) {
    __hip_bfloat16 h = __float2bfloat16(f);
    return *reinterpret_cast<short*>(&h);
}
__device__ __forceinline__ float bf2f(short s) {
    __hip_bfloat16 h = *reinterpret_cast<__hip_bfloat16*>(&s);
    return __bfloat162float(h);
}

#define MFMA16(a, b, c) __builtin_amdgcn_mfma_f32_16x16x32_bf16((a), (b), (c), 0, 0, 0)

// async 16B global->LDS (lds dest: wave-uniform base + lane*16)
__device__ __forceinline__ void gload_lds16(const short* g, short* l) {
    __builtin_amdgcn_global_load_lds(
        (const __attribute__((address_space(1))) void*)g,
        (__attribute__((address_space(3))) void*)l, 16, 0, 0);
}

// ---------------------------------------------------------------------------
// Dtype sniff: fp32 inputs (flag=1) vs bf16 (flag=0).  Kept as a SEPARATE
// 1-block dispatch: R14 measured that folding it into prep (5120 blocks all
// re-reading the same hot 16 KB + per-block barrier/atomic preamble) costs
// ~8 µs more than the dispatch it saves.
// ---------------------------------------------------------------------------
__global__ void sniff_kernel(const unsigned int* __restrict__ xb,
                             unsigned int* __restrict__ flag)
{
    __shared__ int cnt;
    if (threadIdx.x == 0) cnt = 0;
    __syncthreads();
    int c = 0;
    for (int i = threadIdx.x; i < 4096; i += 256) {
        unsigned e = (xb[i] >> 7) & 0xFFu;
        if (e >= 96u && e <= 142u) ++c;
    }
    atomicAdd(&cnt, c);
    __syncthreads();
    if (threadIdx.x == 0) *flag = (cnt < 2048) ? 1u : 0u;
}

// ---------------------------------------------------------------------------
// FUSED prep kernel (cvt_x + both weight transposes).
// Blocks 0..4095:      x -> bf16 copy (8 elems/thread).
// Blocks 4096..4863:   w_attn^T (1024x3072 -> [3072][1024] bf16).
// Blocks 4864..5119:   w_proj^T (1024x1024 -> [1024][1024] bf16).
// ---------------------------------------------------------------------------
__global__ __launch_bounds__(256)
void prep_kernel(const void* __restrict__ x, short* __restrict__ Xb,
                 const void* __restrict__ w_attn, short* __restrict__ Wta,
                 const void* __restrict__ w_proj, short* __restrict__ Wtp,
                 const unsigned int* __restrict__ flagp)
{
    const bool f32in = (*flagp != 0u);
    const int bid = blockIdx.x;
    if (bid < 4096) {
        const size_t i = ((size_t)bid * 256 + threadIdx.x) * 8;
        if (f32in) {
            const float* f = (const float*)x + i;
            f32x4 u0 = *(const f32x4*)f;
            f32x4 u1 = *(const f32x4*)(f + 4);
            short8 v;
#pragma unroll
            for (int j = 0; j < 4; ++j) { v[j] = f2bf(u0[j]); v[j + 4] = f2bf(u1[j]); }
            *(short8*)(Xb + i) = v;
        } else {
            *(short8*)(Xb + i) = *(const short8*)((const short*)x + i);
        }
        return;
    }
    // transpose branches
    __shared__ short tile[64][65];
    const void* in; short* out; int R, C, bx, by;
    if (bid < 4864) {
        const int b2 = bid - 4096;               // 768 blocks = 48 x 16
        in = w_attn; out = Wta; R = 1024; C = 3072;
        bx = (b2 % 48) * 64; by = (b2 / 48) * 64;
    } else {
        const int b2 = bid - 4864;               // 256 blocks = 16 x 16
        in = w_proj; out = Wtp; R = 1024; C = 1024;
        bx = (b2 % 16) * 64; by = (b2 / 16) * 64;
    }
    const int tx = threadIdx.x & 63;
    const int ty = threadIdx.x >> 6;
#pragma unroll
    for (int i = 0; i < 64; i += 4) {
        size_t idx = (size_t)(by + ty + i) * C + bx + tx;
        tile[ty + i][tx] = f32in ? f2bf(((const float*)in)[idx])
                                 : ((const short*)in)[idx];
    }
    __syncthreads();
#pragma unroll
    for (int i = 0; i < 64; i += 4)
        out[(size_t)(bx + ty + i) * R + by + tx] = tile[tx][ty + i];
}

// ---------------------------------------------------------------------------
// GEMM: C = A[M][K] (bf16) @ B (Bt[N][K] bf16) + bias.  128x128 tile, BK=32.
// R12 configuration — measured family floor (97 µs QKV / 33 µs proj).
// Family bracket: R4 2-barrier 103 / R6 dbuf 97 / R7+R12 counted-vmcnt 96-97
// / R13 256x128 106 -> per-step fabric is binding; tile/staging/conflict
// variants are exhausted at this phase count.
//  - 3-buffer counted-vmcnt pipeline (one raw s_barrier per K-step; vmcnt(4)
//    waits own oldest stage only, loads stay in flight across barriers).
//  - T2 bank swizzle (source slot pre-XOR + read slot XOR ((ar>>1)&3)):
//    SQ_LDS_BANK_CONFLICT 6.29M -> 0 (timing-null at 2-phase, kept free).
// EPI=1 (QKV): scatter Q,K [BH][T][64], V transposed [BH][64][T].
//   Q outputs PRE-SCALED by 0.125*log2(e) so attn uses exp2 directly.
// EPI=0 (proj): row-major out, dtype per flag.
// ---------------------------------------------------------------------------
template <int EPI>
__global__ __launch_bounds__(256)
void gemm_kernel(const short* __restrict__ A,
                 const short* __restrict__ Bt,
                 const void* __restrict__ bias,
                 void* __restrict__ O0,
                 short* __restrict__ O1,
                 short* __restrict__ O2,
                 int M, int N, int K,
                 const unsigned int* __restrict__ flagp)
{
    const bool f32io = (*flagp != 0u);
    __shared__ __align__(16) short ldsA[3 * 128 * 32];  // 3-buf [m][k] stride 32
    __shared__ __align__(16) short ldsB[3 * 128 * 32];

    const int tid = threadIdx.x;
    const int lane = tid & 63;
    const int wv = tid >> 6;
    const int wm = (wv & 1) * 64;
    const int wn = (wv >> 1) * 64;
    const int tile_m = blockIdx.y * 128;
    const int tile_n = blockIdx.x * 128;

    f32x4 acc[4][4];
#pragma unroll
    for (int i = 0; i < 4; ++i)
#pragma unroll
        for (int j = 0; j < 4; ++j) acc[i][j] = (f32x4){0.f, 0.f, 0.f, 0.f};

    const int ar = lane & 15;
    const int aq = (lane >> 4) * 8;                  // 16B slot offset, shorts
    const int arx = ((ar >> 1) & 3) << 3;            // read-side XOR, shorts
    const int lrow = lane >> 2;                      // 0..15 staging row
    // pre-swizzled source slot: (lane&3) ^ ((lrow>>1)&3)
    const int scol = (((lane & 3) ^ ((lane >> 3) & 3)) << 3);

    // stage K-chunk k0 into buffer bsel (4 gload_lds16/thread)
    auto stage = [&](int k0, int bsel) {
#pragma unroll
        for (int p = 0; p < 2; ++p) {
            int c = wv * 2 + p;
            int row = c * 16 + lrow;
            gload_lds16(A + (size_t)(tile_m + row) * K + k0 + scol,
                        ldsA + bsel * 4096 + c * 512);
            gload_lds16(Bt + (size_t)(tile_n + row) * K + k0 + scol,
                        ldsB + bsel * 4096 + c * 512);
        }
    };

    stage(0, 0);                          //  4 in flight
    stage(32, 1);                         //  8 in flight
    int cur = 0;

    for (int k0 = 0; k0 < K; k0 += 32) {
        // wait for the OLDEST stage (tile k0) only; keep the next in flight.
        if (k0 + 32 < K) {
            asm volatile("s_waitcnt vmcnt(4)\n\ts_barrier" ::: "memory");
        } else {
            asm volatile("s_waitcnt vmcnt(0)\n\ts_barrier" ::: "memory");
        }

        int nb = cur + 2; if (nb >= 3) nb -= 3;
        if (k0 + 64 < K) stage(k0 + 64, nb);

        const short* Ab = ldsA + cur * 4096;
        const short* Bb = ldsB + cur * 4096;
        short8 af[4], bfr[4];
#pragma unroll
        for (int i = 0; i < 4; ++i)
            af[i] = *(const short8*)(Ab + (wm + i * 16 + ar) * 32 + (aq ^ arx));
#pragma unroll
        for (int j = 0; j < 4; ++j)
            bfr[j] = *(const short8*)(Bb + (wn + j * 16 + ar) * 32 + (aq ^ arx));
#pragma unroll
        for (int i = 0; i < 4; ++i)
#pragma unroll
            for (int j = 0; j < 4; ++j)
                acc[i][j] = MFMA16(af[i], bfr[j], acc[i][j]);

        ++cur; if (cur == 3) cur = 0;
    }

    const int colq = lane & 15;
    const int rowq = (lane >> 4) * 4;
#pragma unroll
    for (int j = 0; j < 4; ++j) {
        int gn = tile_n + wn + j * 16 + colq;
        float bv = f32io ? ((const float*)bias)[gn] : bf2f(((const short*)bias)[gn]);
#pragma unroll
        for (int i = 0; i < 4; ++i) {
#pragma unroll
            for (int r = 0; r < 4; ++r) {
                int gm = tile_m + wm + i * 16 + rowq + r;
                float val = acc[i][j][r] + bv;
                if (EPI == 0) {
                    if (f32io) ((float*)O0)[(size_t)gm * N + gn] = val;
                    else       ((short*)O0)[(size_t)gm * N + gn] = f2bf(val);
                } else {
                    int which = gn >> 10;
                    int c = gn & 1023;
                    int h = c >> 6;
                    int d = c & 63;
                    int b = gm >> 11;
                    int t = gm & 2047;
                    size_t bh = (size_t)(b * 16 + h);
                    // Q pre-scaled: scale * log2(e) = 0.125 * 1.44269504...
                    short o = f2bf(which == 0 ? val * 0.18033688011112042f : val);
                    if (which == 0)      ((short*)O0)[(bh * 2048 + t) * 64 + d] = o;
                    else if (which == 1) O1[(bh * 2048 + t) * 64 + d] = o;
                    else                 O2[(bh * 64 + d) * 2048 + t] = o;  // V^T
                }
            }
        }
    }
}

// ---------------------------------------------------------------------------
// Flash attention, causal, fixed-base softmax (exact: |scores| << 88).
// Q,K: [BH][2048][64], Vt: [BH][64][2048] bf16.  Y: [B][T][C] bf16.
// R6 champion structure (96.7 µs, FETCH 40 MB, VGPR 64) — FROZEN.
//  - LDS exactly 40960 B (K/V dbuf 32768 + XOR-swizzled pbuf 8192);
//    grid 1024 = 4 blocks/CU, launch_bounds(256,4) -> VGPR 64 (no spill;
//    R8/R9 lesson: min-waves bound below live set = scratch spill).
//  - Paired tiles (t, 31-t): 33 uniform steps/block; XCD chunking
//    (8 bh/XCD -> K/V L2-resident; uniform jobs keep the fid->XCD mapping
//    valid — R8 lesson: non-uniform jobs drift it and thrash L2).
//  - 1-barrier dbuf pipeline; mask-split exp path; s_setprio on MFMA.
// ---------------------------------------------------------------------------
__global__ __launch_bounds__(256, 4)
void attn_kernel(const short* __restrict__ Q,
                 const short* __restrict__ Kp_,
                 const short* __restrict__ Vt,
                 short* __restrict__ Y)
{
    __shared__ __align__(16) short ldsK[2 * 64 * 64];  // dbuf [key][d], swizzled
    __shared__ __align__(16) short ldsV[2 * 64 * 64];  // dbuf [d][key], swizzled
    __shared__ __align__(16) short pbuf[4][16 * 64];   // per-wave P, XOR-swizzled

    const int tid = threadIdx.x;
    const int lane = tid & 63;
    const int wv = tid >> 6;                  // 0..3
    const int m16 = lane & 15;
    const int quad = lane >> 4;

    // XCD decode: 1024 blocks; xcd = fid&7; 8 bh per XCD; 16 pairs per bh.
    const int fid = blockIdx.x;
    const int xcd = fid & 7;
    const int slot = fid >> 3;                // 0..127
    const int bh = (xcd << 3) | (slot >> 4);  // 0..63
    const int g = slot & 15;                  // pair id 0..15

    const int b = bh >> 4, h = bh & 15;

    const short* Qp = Q   + (size_t)bh * 2048 * 64;
    const short* Kp = Kp_ + (size_t)bh * 2048 * 64;
    const short* Vp = Vt  + (size_t)bh * 64 * 2048;
    short* pw = pbuf[wv];

    const int srow = lane >> 3;                           // 0..7 within call
    const int sw = (((lane & 7) ^ (srow & 7)) << 3);      // swizzled col, shorts
    const int swr = ((m16 & 7) << 3);                     // K/V read-side XOR
    const int pswr = swr;                                  // pbuf read XOR (q=m16)

    // stage K/V tile at key-offset kb into buffer bsel (4 gload_lds16/thread)
    auto stage = [&](int kb, int bsel) {
#pragma unroll
        for (int p = 0; p < 2; ++p) {
            const int c8 = wv * 2 + p;
            const int row = c8 * 8 + srow;
            gload_lds16(Kp + (size_t)(kb + row) * 64 + sw,
                        ldsK + bsel * 4096 + c8 * 512);
            gload_lds16(Vp + (size_t)row * 2048 + kb + sw,
                        ldsV + bsel * 4096 + c8 * 512);
        }
    };

#pragma unroll
    for (int pass = 0; pass < 2; ++pass) {
        const int t = pass ? (31 - g) : g;        // 64-row tile index 0..31
        const int qbase = t * 64 + wv * 16;       // this wave's 16 q-rows

        stage(0, 0);                              // prologue for this pass

        short8 aq0 = *(const short8*)(Qp + (size_t)(qbase + m16) * 64 + quad * 8);
        short8 aq1 = *(const short8*)(Qp + (size_t)(qbase + m16) * 64 + 32 + quad * 8);

        __syncthreads();                          // implicit vmcnt(0): buf0 ready
        int cur = 0;

        f32x4 o[4];
#pragma unroll
        for (int dt = 0; dt < 4; ++dt) o[dt] = (f32x4){0.f, 0.f, 0.f, 0.f};
        float lrow[4] = {0.f, 0.f, 0.f, 0.f};

        for (int kt = 0; kt <= t; ++kt) {
            const int kb = kt << 6;
            if (kt < t) stage(kb + 64, cur ^ 1);  // issue-early (overlaps)

            const short* kbase = ldsK + cur * 4096;
            const short* vbase = ldsV + cur * 4096;

            // ---- QK^T: 4 key-blocks x 2 k-chunks ----
            f32x4 s[4];
            __builtin_amdgcn_s_setprio(1);
#pragma unroll
            for (int c = 0; c < 4; ++c) {
                const short* kr = kbase + (c * 16 + m16) * 64;
                short8 kf0 = *(const short8*)(kr + ((quad * 8) ^ swr));
                short8 kf1 = *(const short8*)(kr + ((quad * 8 + 32) ^ swr));
                f32x4 z = (f32x4){0.f, 0.f, 0.f, 0.f};
                z = MFMA16(aq0, kf0, z);
                z = MFMA16(aq1, kf1, z);
                s[c] = z;
            }
            __builtin_amdgcn_s_setprio(0);

            // ---- exp + P store (fixed-base; Q pre-scaled).  Mask-split:
            // kt < t  -> causal mask provably dead (kb+63 < qbase).
            // kt == t -> masked path (runs once per pass). ----
            if (kt < t) {
#pragma unroll
                for (int c = 0; c < 4; ++c) {
#pragma unroll
                    for (int r = 0; r < 4; ++r) {
                        const int qrow = quad * 4 + r;
                        float p = exp2f(s[c][r]);
                        lrow[r] += p;
                        pw[qrow * 64 + ((c * 16 + m16) ^ ((qrow & 7) << 3))] = f2bf(p);
                    }
                }
            } else {
#pragma unroll
                for (int c = 0; c < 4; ++c) {
                    const int key = kb + c * 16 + m16;
                    const bool needmask = (kb + c * 16 + 15 > qbase);
#pragma unroll
                    for (int r = 0; r < 4; ++r) {
                        const int qrow = quad * 4 + r;
                        float p = exp2f(s[c][r]);
                        if (needmask && key > qbase + qrow) p = 0.f;
                        lrow[r] += p;
                        pw[qrow * 64 + ((c * 16 + m16) ^ ((qrow & 7) << 3))] = f2bf(p);
                    }
                }
            }

            // P (C-layout) -> A-operand via per-wave LDS round-trip
            asm volatile("" ::: "memory");
            short8 ap0 = *(const short8*)(pw + m16 * 64 + ((quad * 8) ^ pswr));
            short8 ap1 = *(const short8*)(pw + m16 * 64 + ((quad * 8 + 32) ^ pswr));
            asm volatile("" ::: "memory");

            // ---- PV: 4 d-blocks x 2 k-chunks ----
            __builtin_amdgcn_s_setprio(1);
#pragma unroll
            for (int dt = 0; dt < 4; ++dt) {
                const short* vr = vbase + (dt * 16 + m16) * 64;
                short8 vf0 = *(const short8*)(vr + ((quad * 8) ^ swr));
                short8 vf1 = *(const short8*)(vr + ((quad * 8 + 32) ^ swr));
                o[dt] = MFMA16(ap0, vf0, o[dt]);
                o[dt] = MFMA16(ap1, vf1, o[dt]);
            }
            __builtin_amdgcn_s_setprio(0);

            __syncthreads();              // one barrier/step: drains next-stage
            cur ^= 1;
        }

        // row-sum reduce over the 16 key-lanes (xor within m16 group)
        float linv[4];
#pragma unroll
        for (int r = 0; r < 4; ++r) {
            float sm = lrow[r];
#pragma unroll
            for (int off = 1; off < 16; off <<= 1)
                sm += __shfl_xor(sm, off);
            linv[r] = 1.0f / sm;
        }
#pragma unroll
        for (int dt = 0; dt < 4; ++dt) {
#pragma unroll
            for (int r = 0; r < 4; ++r) {
                int row = qbase + quad * 4 + r;
                int col = h * 64 + dt * 16 + m16;
                Y[((size_t)(b * 2048 + row)) * 1024 + col] = f2bf(o[dt][r] * linv[r]);
            }
        }
        // pass boundary safe: trailing __syncthreads of the kt-loop ran after
        // all LDS reads of the final tile.
    }
}

// ---------------------------------------------------------------------------
extern "C" void kernel_launch(void* const* d_in, const int* in_sizes, int n_in,
                              void* d_out, int out_size, void* d_ws, size_t ws_size,
                              hipStream_t stream)
{
    const void* x      = d_in[0];
    const void* w_attn = d_in[1];
    const void* b_attn = d_in[2];
    const void* w_proj = d_in[3];
    const void* b_proj = d_in[4];

    char* ws = (char*)d_ws;
    unsigned int* flag = (unsigned int*)(ws + 0);
    short* Wta = (short*)(ws + 256);
    short* Wtp = (short*)(ws + 6291712);
    short* Qb  = (short*)(ws + 8388864);
    short* Kb  = (short*)(ws + 25166080);
    short* Vtb = (short*)(ws + 41943296);
    short* Yb  = (short*)(ws + 58720512);
    // Xb (bf16 x) REUSES the Yb slot: Xb's lifetime (prep -> QKV gemm)
    // ends before Yb's begins (attn -> proj gemm); same stream, sequential.
    short* Xb  = (short*)(ws + 58720512);

    sniff_kernel<<<1, 256, 0, stream>>>((const unsigned int*)x, flag);
    prep_kernel<<<dim3(5120), 256, 0, stream>>>(x, Xb, w_attn, Wta, w_proj, Wtp, flag);
    gemm_kernel<1><<<dim3(24, 64), 256, 0, stream>>>(Xb, Wta, b_attn, Qb, Kb, Vtb,
                                                     8192, 3072, 1024, flag);
    attn_kernel<<<dim3(1024), 256, 0, stream>>>(Qb, Kb, Vtb, Yb);
    gemm_kernel<0><<<dim3(8, 64), 256, 0, stream>>>(Yb, Wtp, b_proj, d_out, nullptr, nullptr,
                                                    8192, 1024, 1024, flag);
}